// Round 9
// baseline (209.268 us; speedup 1.0000x reference)
//
#include <hip/hip_runtime.h>
#include <hip/hip_bf16.h>
#include <stdint.h>

typedef __attribute__((ext_vector_type(8))) __bf16 bf16x8;
typedef __attribute__((ext_vector_type(4))) float floatx4;

#define EPS 1e-5f

__device__ __forceinline__ unsigned short f2bf(float f) {
    union { float f; unsigned int u; } x; x.f = f;
    unsigned int r = x.u + 0x7fffu + ((x.u >> 16) & 1u);
    return (unsigned short)(r >> 16);
}

__device__ __forceinline__ float bf2f(unsigned int u) {
    union { unsigned int u; float f; } x; x.u = u << 16; return x.f;
}

struct Params {
    const float* x_in;
    const int*   knn;
    const float* w1s[3];   // [128][512]
    const float* w2s[3];   // [512][128]
    const float* vws[2];   // [128][128]
    unsigned short* W1P[3];
    unsigned short* W2P[3];
    unsigned short* VTP[2];
    const float* b1s[3];
    const float* b2s[3];
    const float* gs[3];
    const float* bes[3];
    const float* ms[3];
    const float* vvs[3];
    const float* vbb[2];
    const float* vgg[2];
    const float* vbt[2];
    const float* vmm[2];
    const float* vva[2];
    float* xf;
};

// ---------------- pack weights, DEST-major (coalesced uint4 stores) --------
// Validated R3-R6. Fragment layout (consumer side):
// W1P short-addr d = hf*16384 + w*2048 + ks*512 + q*128 + ln*8 + j
//   holds W1[k=32ks+8q+j][h=128hf+16w+ln]   (src [128][512], idx=k*512+h)
// W2P same d-layout, holds W2[h=128hf+32ks+8q+j][c=16w+ln]  (src idx=h*128+c)
// VTP d = w*2048+ks*512+q*128+ln*8+j, holds Wv[k=32ks+8q+j][c=16w+ln]
__global__ __launch_bounds__(256) void pack2(Params P) {
    const int gtid = blockIdx.x * 256 + threadIdx.x;
    unsigned short v[8];
    if (gtid < 24576) {                       // W1 x3: 3*8192 fragments
        const int t = gtid >> 13;
        const int d = (gtid & 8191) << 3;
        const int hf = d >> 14, w = (d >> 11) & 7, ks = (d >> 9) & 3,
                  q = (d >> 7) & 3, ln = (d >> 3) & 15;
        const float* s1 = P.w1s[t];
        const int hcol = 128 * hf + 16 * w + ln;
        const int kb   = 32 * ks + 8 * q;
#pragma unroll
        for (int j = 0; j < 8; ++j) v[j] = f2bf(s1[(kb + j) * 512 + hcol]);
        uint4 pk;
        pk.x = v[0] | ((unsigned)v[1] << 16); pk.y = v[2] | ((unsigned)v[3] << 16);
        pk.z = v[4] | ((unsigned)v[5] << 16); pk.w = v[6] | ((unsigned)v[7] << 16);
        *(uint4*)&P.W1P[t][d] = pk;
    } else if (gtid < 49152) {                // W2 x3: 3*8192 fragments
        const int g = gtid - 24576;
        const int t = g >> 13;
        const int d = (g & 8191) << 3;
        const int hf = d >> 14, w = (d >> 11) & 7, ks = (d >> 9) & 3,
                  q = (d >> 7) & 3, ln = (d >> 3) & 15;
        const float* s2 = P.w2s[t];
        const int col = 16 * w + ln;
        const int hb  = 128 * hf + 32 * ks + 8 * q;
#pragma unroll
        for (int j = 0; j < 8; ++j) v[j] = f2bf(s2[(hb + j) * 128 + col]);
        uint4 pk;
        pk.x = v[0] | ((unsigned)v[1] << 16); pk.y = v[2] | ((unsigned)v[3] << 16);
        pk.z = v[4] | ((unsigned)v[5] << 16); pk.w = v[6] | ((unsigned)v[7] << 16);
        *(uint4*)&P.W2P[t][d] = pk;
    } else if (gtid < 53248) {                // VT x2: 2*2048 fragments
        const int g = gtid - 49152;
        const int t = g >> 11;
        const int d = (g & 2047) << 3;
        const int w = (d >> 11) & 7, ks = (d >> 9) & 3,
                  q = (d >> 7) & 3, ln = (d >> 3) & 15;
        const float* sv = P.vws[t];
        const int col = 16 * w + ln;
        const int kb  = 32 * ks + 8 * q;
#pragma unroll
        for (int j = 0; j < 8; ++j) v[j] = f2bf(sv[(kb + j) * 128 + col]);
        uint4 pk;
        pk.x = v[0] | ((unsigned)v[1] << 16); pk.y = v[2] | ((unsigned)v[3] << 16);
        pk.z = v[4] | ((unsigned)v[5] << 16); pk.w = v[6] | ((unsigned)v[7] << 16);
        *(uint4*)&P.VTP[t][d] = pk;
    }
}

// ---------------- fused stage kernel (512 thr = 8 waves, 64 points) --------
// R6 layout EXACTLY (R8's odd-stride padding regressed 183->209 us: with
// stride 17 ≡ 1 mod 8 the bank-set becomes (row+chunk)&7 on reads AND
// writes, and x17/x132 addressing adds VALU to every hot ds address —
// reverted). R9 change: GEMM1's xt B-operand fragments are hf-INVARIANT,
// so hoist all 16 bf16x8 (64 VGPR) into registers once after the tile
// barrier and reuse across the 4 hf slices: per-wave ds_read_b128 count
// 144 -> 96 (-33%), conflict exposure down proportionally. VGPR ~116 <
// 128 cap of __launch_bounds__(512,4) — no spill expected.
template <int LOADX, int TE, int TF, int TV>
__global__ __launch_bounds__(512, 4)
void stage(Params P, const float* __restrict__ xold_g,
           const unsigned short* __restrict__ VbIn,
           unsigned short* __restrict__ VbOut)
{
    __shared__ __align__(16) unsigned short xt[8192];   // 16 KB
    __shared__ __align__(16) float xf32[8192];          // 32 KB
    __shared__ __align__(16) uint2 ht2[2048];           // 16 KB
    const int tid  = threadIdx.x;
    const int lane = tid & 63;
    const int w    = tid >> 6;       // wave 0..7
    const int q    = lane >> 4;
    const int ln   = lane & 15;
    const int sw   = ln & 7;
    const int phys = blockIdx.x;
    const int bid  = (phys & 7) * 64 + (phys >> 3);   // XCD-local batches
    const int p0   = bid << 6;
    const floatx4 zero = {0.f, 0.f, 0.f, 0.f};

    if constexpr (LOADX) {
        const int r = tid >> 3, seg = tid & 7;
        const float4* src = (const float4*)(xold_g + (size_t)(p0 + r) * 128 + seg * 16);
        float4* dstf = (float4*)&xf32[r * 128 + seg * 16];
#pragma unroll
        for (int i = 0; i < 2; ++i) {
            float4 a = src[2 * i];
            float4 b = src[2 * i + 1];
            dstf[2 * i]     = a;
            dstf[2 * i + 1] = b;
            int kq = seg * 2 + i;
            uint4 pk;
            pk.x = (unsigned int)f2bf(a.x) | ((unsigned int)f2bf(a.y) << 16);
            pk.y = (unsigned int)f2bf(a.z) | ((unsigned int)f2bf(a.w) << 16);
            pk.z = (unsigned int)f2bf(b.x) | ((unsigned int)f2bf(b.y) << 16);
            pk.w = (unsigned int)f2bf(b.z) | ((unsigned int)f2bf(b.w) << 16);
            *(uint4*)&xt[(r * 16 + (kq ^ (r & 7))) * 8] = pk;
        }
    }

    if constexpr (TE >= 0) {
        const int c0 = lane << 1;
        float2 gv = *(const float2*)(P.vgg[TE] + c0);
        float2 bv = *(const float2*)(P.vbt[TE] + c0);
        float2 mv = *(const float2*)(P.vmm[TE] + c0);
        float2 vv = *(const float2*)(P.vva[TE] + c0);
        const float sc0 = gv.x * rsqrtf(vv.x + EPS);
        const float sc1 = gv.y * rsqrtf(vv.y + EPS);
#pragma unroll
        for (int it = 0; it < 8; ++it) {
            const int pl = it * 8 + w;
            const int p  = p0 + pl;
            const int b  = p >> 12;
            const size_t rowoff = (size_t)p * 128 + c0;
            unsigned int su = *(const unsigned int*)(VbIn + rowoff);
            const int4* kp4 = (const int4*)(P.knn + (size_t)p * 16);
            int4 ka = kp4[0], kb = kp4[1], kc = kp4[2], kd = kp4[3];
            const unsigned short* vbase = VbIn + (((size_t)b << 12) << 7) + c0;
            float m0 = -3.4e38f, m1 = -3.4e38f;
            unsigned int u;
#define GATH(IDX) u = *(const unsigned int*)(vbase + ((size_t)(IDX) << 7)); \
            m0 = fmaxf(m0, bf2f(u & 0xffffu)); m1 = fmaxf(m1, bf2f(u >> 16));
            GATH(ka.x) GATH(ka.y) GATH(ka.z) GATH(ka.w)
            GATH(kb.x) GATH(kb.y) GATH(kb.z) GATH(kb.w)
            GATH(kc.x) GATH(kc.y) GATH(kc.z) GATH(kc.w)
            GATH(kd.x) GATH(kd.y) GATH(kd.z) GATH(kd.w)
#undef GATH
            float s0 = bf2f(su & 0xffffu), s1 = bf2f(su >> 16);
            float y0 = (m0 - s0 - mv.x) * sc0 + bv.x;
            float y1 = (m1 - s1 - mv.y) * sc1 + bv.y;
            float2 xv = *(const float2*)(xold_g + rowoff);
            float xn0 = xv.x + y0, xn1 = xv.y + y1;
            *(float2*)&xf32[pl * 128 + c0] = make_float2(xn0, xn1);
            unsigned int pk = (unsigned int)f2bf(xn0) | ((unsigned int)f2bf(xn1) << 16);
            ((unsigned int*)xt)[(pl * 16 + ((lane >> 2) ^ (pl & 7))) * 4 + (lane & 3)] = pk;
        }
    }
    __syncthreads();

    // ---- hoist GEMM1's hf-invariant xt fragments into registers (once) ----
    bf16x8 xtr[16];
#pragma unroll
    for (int nt = 0; nt < 4; ++nt)
#pragma unroll
        for (int ks = 0; ks < 4; ++ks)
            xtr[nt * 4 + ks] = *(const bf16x8*)&xt[((16 * nt + ln) * 16 + ((4 * ks + q) ^ sw)) * 8];

    // ---------------- FFN, hidden-split x4 ----------------
    floatx4 acc2[4];
#pragma unroll
    for (int i = 0; i < 4; ++i) acc2[i] = zero;

    const unsigned short* W1 = P.W1P[TF];
    const unsigned short* W2 = P.W2P[TF];
    const float* b1 = P.b1s[TF];

#pragma unroll
    for (int hf = 0; hf < 4; ++hf) {
        // GEMM1: h^T slice (M=128 hid, N=64 pts, K=128); wave w: hid 16w..16w+15
        floatx4 acc1[4];
#pragma unroll
        for (int i = 0; i < 4; ++i) acc1[i] = zero;
        const unsigned short* a1 = W1 + hf * 16384 + w * 2048 + q * 128 + ln * 8;
#pragma unroll
        for (int ks = 0; ks < 4; ++ks) {
            bf16x8 af = *(const bf16x8*)(a1 + ks * 512);
#pragma unroll
            for (int nt = 0; nt < 4; ++nt) {
                acc1[nt] = __builtin_amdgcn_mfma_f32_16x16x32_bf16(af, xtr[nt * 4 + ks], acc1[nt], 0, 0, 0);
            }
        }
        // epilogue1: +b1, relu, pack 4 consecutive hid -> ht
        {
            const int hid0 = 16 * w + 4 * q;          // within this 128-slice
            const int ghid = 128 * hf + hid0;
            const float bv0 = b1[ghid + 0], bv1 = b1[ghid + 1];
            const float bv2 = b1[ghid + 2], bv3 = b1[ghid + 3];
            const int c16  = hid0 >> 3;
            const int half = q & 1;
#pragma unroll
            for (int nt = 0; nt < 4; ++nt) {
                const int pt = 16 * nt + ln;
                float v0 = acc1[nt][0] + bv0; v0 = v0 > 0.f ? v0 : 0.f;
                float v1 = acc1[nt][1] + bv1; v1 = v1 > 0.f ? v1 : 0.f;
                float v2 = acc1[nt][2] + bv2; v2 = v2 > 0.f ? v2 : 0.f;
                float v3 = acc1[nt][3] + bv3; v3 = v3 > 0.f ? v3 : 0.f;
                uint2 pk;
                pk.x = (unsigned int)f2bf(v0) | ((unsigned int)f2bf(v1) << 16);
                pk.y = (unsigned int)f2bf(v2) | ((unsigned int)f2bf(v3) << 16);
                ht2[(pt * 16 + (c16 ^ (pt & 7))) * 2 + half] = pk;
            }
        }
        __syncthreads();
        // GEMM2: y += h_slice @ W2_slice (M=64 pts, N=128 ch, K=128); wave w: ch 16w..
        const unsigned short* b2b = W2 + hf * 16384 + w * 2048 + q * 128 + ln * 8;
#pragma unroll
        for (int ks = 0; ks < 4; ++ks) {
            bf16x8 bw = *(const bf16x8*)(b2b + ks * 512);
#pragma unroll
            for (int mt = 0; mt < 4; ++mt) {
                bf16x8 ah = *(const bf16x8*)&ht2[((16 * mt + ln) * 16 + ((4 * ks + q) ^ sw)) * 2];
                acc2[mt] = __builtin_amdgcn_mfma_f32_16x16x32_bf16(ah, bw, acc2[mt], 0, 0, 0);
            }
        }
        __syncthreads();
    }

    // epilogue2: +b2, BN, residual (fp32 base from LDS), write xf (+xt)
    {
        const float* b2   = P.b2s[TF];
        const float* gam  = P.gs[TF];
        const float* bet  = P.bes[TF];
        const float* mean = P.ms[TF];
        const float* var  = P.vvs[TF];
        const int c = 16 * w + ln;
        const float bia = b2[c];
        const float sc  = gam[c] * rsqrtf(var[c] + EPS);
        const float bb  = bet[c];
        const float mu  = mean[c];
#pragma unroll
        for (int mt = 0; mt < 4; ++mt) {
#pragma unroll
            for (int r = 0; r < 4; ++r) {
                const int rl = 16 * mt + 4 * q + r;
                float v  = acc2[mt][r] + bia;
                float y  = (v - mu) * sc + bb;
                float xn = xf32[rl * 128 + c] + y;
                P.xf[(size_t)(p0 + rl) * 128 + c] = xn;
                if constexpr (TV >= 0)
                    xt[(rl * 16 + ((c >> 3) ^ (rl & 7))) * 8 + (c & 7)] = f2bf(xn);
            }
        }
    }

    // ---------------- VFR linear ----------------
    if constexpr (TV >= 0) {
        __syncthreads();
        const unsigned short* VT = P.VTP[TV];
        const float* vb = P.vbb[TV];
        floatx4 acc[4];
#pragma unroll
        for (int i = 0; i < 4; ++i) acc[i] = zero;
        const unsigned short* bb2 = VT + w * 2048 + q * 128 + ln * 8;
#pragma unroll
        for (int ks = 0; ks < 4; ++ks) {
            bf16x8 bw = *(const bf16x8*)(bb2 + ks * 512);
#pragma unroll
            for (int mt = 0; mt < 4; ++mt) {
                bf16x8 ax = *(const bf16x8*)&xt[((16 * mt + ln) * 16 + ((4 * ks + q) ^ sw)) * 8];
                acc[mt] = __builtin_amdgcn_mfma_f32_16x16x32_bf16(ax, bw, acc[mt], 0, 0, 0);
            }
        }
        const int c = 16 * w + ln;
        const float bia = vb[c];
#pragma unroll
        for (int mt = 0; mt < 4; ++mt)
#pragma unroll
            for (int r = 0; r < 4; ++r)
                VbOut[(size_t)(p0 + 16 * mt + 4 * q + r) * 128 + c] = f2bf(acc[mt][r] + bia);
    }
}

// ---------------- launch ----------------
extern "C" void kernel_launch(void* const* d_in, const int* in_sizes, int n_in,
                              void* d_out, int out_size, void* d_ws, size_t ws_size,
                              hipStream_t stream)
{
    Params p;
    p.x_in = (const float*)d_in[0];
    p.knn  = (const int*)d_in[1];
    const float* w1  = (const float*)d_in[2];
    const float* b1  = (const float*)d_in[3];
    const float* w2  = (const float*)d_in[4];
    const float* b2  = (const float*)d_in[5];
    const float* g0  = (const float*)d_in[6];
    const float* be0 = (const float*)d_in[7];
    const float* m0p = (const float*)d_in[8];
    const float* v0p = (const float*)d_in[9];
    const float* vw  = (const float*)d_in[10];
    const float* vbp = (const float*)d_in[11];
    const float* vgp = (const float*)d_in[12];
    const float* vbe = (const float*)d_in[13];
    const float* vmp = (const float*)d_in[14];
    const float* vvp = (const float*)d_in[15];
    const float* fw1 = (const float*)d_in[16];
    const float* fb1 = (const float*)d_in[17];
    const float* fw2 = (const float*)d_in[18];
    const float* fb2 = (const float*)d_in[19];
    const float* fg  = (const float*)d_in[20];
    const float* fbe = (const float*)d_in[21];
    const float* fm  = (const float*)d_in[22];
    const float* fv  = (const float*)d_in[23];

    p.w1s[0] = w1;  p.w1s[1] = fw1; p.w1s[2] = fw1 + 65536;
    p.w2s[0] = w2;  p.w2s[1] = fw2; p.w2s[2] = fw2 + 65536;
    p.vws[0] = vw;  p.vws[1] = vw + 16384;
    p.b1s[0] = b1;  p.b1s[1] = fb1; p.b1s[2] = fb1 + 512;
    p.b2s[0] = b2;  p.b2s[1] = fb2; p.b2s[2] = fb2 + 128;
    p.gs[0]  = g0;  p.gs[1]  = fg;  p.gs[2]  = fg + 128;
    p.bes[0] = be0; p.bes[1] = fbe; p.bes[2] = fbe + 128;
    p.ms[0]  = m0p; p.ms[1]  = fm;  p.ms[2]  = fm + 128;
    p.vvs[0] = v0p; p.vvs[1] = fv;  p.vvs[2] = fv + 128;
    p.vbb[0] = vbp; p.vbb[1] = vbp + 128;
    p.vgg[0] = vgp; p.vgg[1] = vgp + 128;
    p.vbt[0] = vbe; p.vbt[1] = vbe + 128;
    p.vmm[0] = vmp; p.vmm[1] = vmp + 128;
    p.vva[0] = vvp; p.vva[1] = vvp + 128;

    char* ws = (char*)d_ws;
    unsigned short* Vb0 = (unsigned short*)ws;                          // 8 MiB
    unsigned short* Vb1 = (unsigned short*)(ws + (size_t)(8 << 20));    // 8 MiB
    unsigned short* u   = (unsigned short*)(ws + (size_t)(16 << 20));   // packed weights
    for (int i = 0; i < 3; ++i) p.W1P[i] = u + i * 65536;
    for (int i = 0; i < 3; ++i) p.W2P[i] = u + 196608 + i * 65536;
    for (int i = 0; i < 2; ++i) p.VTP[i] = u + 393216 + i * 16384;
    p.xf = (float*)d_out;

    pack2<<<dim3(208), 256, 0, stream>>>(p);
    stage<1, -1, 0, 0><<<dim3(512), 512, 0, stream>>>(p, p.x_in, nullptr, Vb0);
    stage<0,  0, 1, 1><<<dim3(512), 512, 0, stream>>>(p, p.xf, Vb0, Vb1);
    stage<0,  1, 2, -1><<<dim3(512), 512, 0, stream>>>(p, p.xf, Vb1, nullptr);
}

// Round 10
// 200.923 us; speedup vs baseline: 1.0415x; 1.0415x over previous
//
#include <hip/hip_runtime.h>
#include <hip/hip_bf16.h>
#include <stdint.h>

typedef __attribute__((ext_vector_type(8))) __bf16 bf16x8;
typedef __attribute__((ext_vector_type(4))) float floatx4;

#define EPS 1e-5f

__device__ __forceinline__ unsigned short f2bf(float f) {
    union { float f; unsigned int u; } x; x.f = f;
    unsigned int r = x.u + 0x7fffu + ((x.u >> 16) & 1u);
    return (unsigned short)(r >> 16);
}

__device__ __forceinline__ float bf2f(unsigned int u) {
    union { unsigned int u; float f; } x; x.u = u << 16; return x.f;
}

struct Params {
    const float* x_in;
    const int*   knn;
    const float* w1s[3];   // [128][512]
    const float* w2s[3];   // [512][128]
    const float* vws[2];   // [128][128]
    unsigned short* W1P[3];
    unsigned short* W2P[3];
    unsigned short* VTP[2];
    const float* b1s[3];
    const float* b2s[3];
    const float* gs[3];
    const float* bes[3];
    const float* ms[3];
    const float* vvs[3];
    const float* vbb[2];
    const float* vgg[2];
    const float* vbt[2];
    const float* vmm[2];
    const float* vva[2];
    float* xf;
};

// ---------------- pack weights, DEST-major (coalesced uint4 stores) --------
// Validated R3-R9. Fragment layout (consumer side):
// W1P short-addr d = hf*16384 + w*2048 + ks*512 + q*128 + ln*8 + j
//   holds W1[k=32ks+8q+j][h=128hf+16w+ln]   (src [128][512], idx=k*512+h)
// W2P same d-layout, holds W2[h=128hf+32ks+8q+j][c=16w+ln]  (src idx=h*128+c)
// VTP d = w*2048+ks*512+q*128+ln*8+j, holds Wv[k=32ks+8q+j][c=16w+ln]
__global__ __launch_bounds__(256) void pack2(Params P) {
    const int gtid = blockIdx.x * 256 + threadIdx.x;
    unsigned short v[8];
    if (gtid < 24576) {                       // W1 x3: 3*8192 fragments
        const int t = gtid >> 13;
        const int d = (gtid & 8191) << 3;
        const int hf = d >> 14, w = (d >> 11) & 7, ks = (d >> 9) & 3,
                  q = (d >> 7) & 3, ln = (d >> 3) & 15;
        const float* s1 = P.w1s[t];
        const int hcol = 128 * hf + 16 * w + ln;
        const int kb   = 32 * ks + 8 * q;
#pragma unroll
        for (int j = 0; j < 8; ++j) v[j] = f2bf(s1[(kb + j) * 512 + hcol]);
        uint4 pk;
        pk.x = v[0] | ((unsigned)v[1] << 16); pk.y = v[2] | ((unsigned)v[3] << 16);
        pk.z = v[4] | ((unsigned)v[5] << 16); pk.w = v[6] | ((unsigned)v[7] << 16);
        *(uint4*)&P.W1P[t][d] = pk;
    } else if (gtid < 49152) {                // W2 x3: 3*8192 fragments
        const int g = gtid - 24576;
        const int t = g >> 13;
        const int d = (g & 8191) << 3;
        const int hf = d >> 14, w = (d >> 11) & 7, ks = (d >> 9) & 3,
                  q = (d >> 7) & 3, ln = (d >> 3) & 15;
        const float* s2 = P.w2s[t];
        const int col = 16 * w + ln;
        const int hb  = 128 * hf + 32 * ks + 8 * q;
#pragma unroll
        for (int j = 0; j < 8; ++j) v[j] = f2bf(s2[(hb + j) * 128 + col]);
        uint4 pk;
        pk.x = v[0] | ((unsigned)v[1] << 16); pk.y = v[2] | ((unsigned)v[3] << 16);
        pk.z = v[4] | ((unsigned)v[5] << 16); pk.w = v[6] | ((unsigned)v[7] << 16);
        *(uint4*)&P.W2P[t][d] = pk;
    } else if (gtid < 53248) {                // VT x2: 2*2048 fragments
        const int g = gtid - 49152;
        const int t = g >> 11;
        const int d = (g & 2047) << 3;
        const int w = (d >> 11) & 7, ks = (d >> 9) & 3,
                  q = (d >> 7) & 3, ln = (d >> 3) & 15;
        const float* sv = P.vws[t];
        const int col = 16 * w + ln;
        const int kb  = 32 * ks + 8 * q;
#pragma unroll
        for (int j = 0; j < 8; ++j) v[j] = f2bf(sv[(kb + j) * 128 + col]);
        uint4 pk;
        pk.x = v[0] | ((unsigned)v[1] << 16); pk.y = v[2] | ((unsigned)v[3] << 16);
        pk.z = v[4] | ((unsigned)v[5] << 16); pk.w = v[6] | ((unsigned)v[7] << 16);
        *(uint4*)&P.VTP[t][d] = pk;
    }
}

// ---------------- stage kernel: 32-POINT tiles, 4 blocks/CU ----------------
// R9 PMC verdict: MfmaUtil 6%, VALUBusy 21%, HBM 8%, Occupancy 35% —
// latency-bound, nothing saturated. (R9's xtr hoist: conflicts 3.2M->1.7M
// yet +7us/stage -> LDS conflicts NOT on critical path; reverted.)
// R10: halve the tile to 32 pts/block, grid 1024 = 4 blocks/CU exactly
// (no tail). Inner fragment formulas byte-identical to R6; only loop
// bounds halve (nt,mt<2; TE it<4) and LOADX remaps. LDS 32 KB/block
// (xt 8K + xf32 16K + ht 8K); __launch_bounds__(512,8) caps unified regs
// at 64 (R6 body was 52 VGPR, accs halved -> fits). 32 waves/CU target.
// XCD swizzle: bid = (phys&7)*128 + phys>>3 => XCD i serves batch i.
template <int LOADX, int TE, int TF, int TV>
__global__ __launch_bounds__(512, 8)
void stage(Params P, const float* __restrict__ xold_g,
           const unsigned short* __restrict__ VbIn,
           unsigned short* __restrict__ VbOut)
{
    __shared__ __align__(16) unsigned short xt[4096];   // 32 x 16ch x 8sh, 8 KB
    __shared__ __align__(16) float xf32[4096];          // 32 x 128, 16 KB
    __shared__ __align__(16) uint2 ht2[1024];           // 32 x 16ch x 2, 8 KB
    const int tid  = threadIdx.x;
    const int lane = tid & 63;
    const int w    = tid >> 6;       // wave 0..7
    const int q    = lane >> 4;
    const int ln   = lane & 15;
    const int sw   = ln & 7;
    const int phys = blockIdx.x;
    const int bid  = (phys & 7) * 128 + (phys >> 3);  // XCD-local batches
    const int p0   = bid << 5;                        // 32 points per block
    const floatx4 zero = {0.f, 0.f, 0.f, 0.f};

    if constexpr (LOADX) {
        const int r = tid >> 4, seg = tid & 15;       // 32 rows x 16 segs(8 floats)
        const float4* src = (const float4*)(xold_g + (size_t)(p0 + r) * 128 + seg * 8);
        float4 a = src[0];
        float4 b = src[1];
        float4* dstf = (float4*)&xf32[r * 128 + seg * 8];
        dstf[0] = a;
        dstf[1] = b;
        uint4 pk;
        pk.x = (unsigned int)f2bf(a.x) | ((unsigned int)f2bf(a.y) << 16);
        pk.y = (unsigned int)f2bf(a.z) | ((unsigned int)f2bf(a.w) << 16);
        pk.z = (unsigned int)f2bf(b.x) | ((unsigned int)f2bf(b.y) << 16);
        pk.w = (unsigned int)f2bf(b.z) | ((unsigned int)f2bf(b.w) << 16);
        *(uint4*)&xt[(r * 16 + (seg ^ (r & 7))) * 8] = pk;
    }

    if constexpr (TE >= 0) {
        const int c0 = lane << 1;
        float2 gv = *(const float2*)(P.vgg[TE] + c0);
        float2 bv = *(const float2*)(P.vbt[TE] + c0);
        float2 mv = *(const float2*)(P.vmm[TE] + c0);
        float2 vv = *(const float2*)(P.vva[TE] + c0);
        const float sc0 = gv.x * rsqrtf(vv.x + EPS);
        const float sc1 = gv.y * rsqrtf(vv.y + EPS);
#pragma unroll
        for (int it = 0; it < 4; ++it) {
            const int pl = it * 8 + w;
            const int p  = p0 + pl;
            const int b  = p >> 12;
            const size_t rowoff = (size_t)p * 128 + c0;
            unsigned int su = *(const unsigned int*)(VbIn + rowoff);
            const int4* kp4 = (const int4*)(P.knn + (size_t)p * 16);
            int4 ka = kp4[0], kb = kp4[1], kc = kp4[2], kd = kp4[3];
            const unsigned short* vbase = VbIn + (((size_t)b << 12) << 7) + c0;
            float m0 = -3.4e38f, m1 = -3.4e38f;
            unsigned int u;
#define GATH(IDX) u = *(const unsigned int*)(vbase + ((size_t)(IDX) << 7)); \
            m0 = fmaxf(m0, bf2f(u & 0xffffu)); m1 = fmaxf(m1, bf2f(u >> 16));
            GATH(ka.x) GATH(ka.y) GATH(ka.z) GATH(ka.w)
            GATH(kb.x) GATH(kb.y) GATH(kb.z) GATH(kb.w)
            GATH(kc.x) GATH(kc.y) GATH(kc.z) GATH(kc.w)
            GATH(kd.x) GATH(kd.y) GATH(kd.z) GATH(kd.w)
#undef GATH
            float s0 = bf2f(su & 0xffffu), s1 = bf2f(su >> 16);
            float y0 = (m0 - s0 - mv.x) * sc0 + bv.x;
            float y1 = (m1 - s1 - mv.y) * sc1 + bv.y;
            float2 xv = *(const float2*)(xold_g + rowoff);
            float xn0 = xv.x + y0, xn1 = xv.y + y1;
            *(float2*)&xf32[pl * 128 + c0] = make_float2(xn0, xn1);
            unsigned int pk = (unsigned int)f2bf(xn0) | ((unsigned int)f2bf(xn1) << 16);
            ((unsigned int*)xt)[(pl * 16 + ((lane >> 2) ^ (pl & 7))) * 4 + (lane & 3)] = pk;
        }
    }
    __syncthreads();

    // ---------------- FFN, hidden-split x4 (N=32 pts) ----------------
    floatx4 acc2[2];
#pragma unroll
    for (int i = 0; i < 2; ++i) acc2[i] = zero;

    const unsigned short* W1 = P.W1P[TF];
    const unsigned short* W2 = P.W2P[TF];
    const float* b1 = P.b1s[TF];

#pragma unroll
    for (int hf = 0; hf < 4; ++hf) {
        // GEMM1: h^T slice (M=128 hid, N=32 pts, K=128); wave w: hid 16w..16w+15
        floatx4 acc1[2];
#pragma unroll
        for (int i = 0; i < 2; ++i) acc1[i] = zero;
        const unsigned short* a1 = W1 + hf * 16384 + w * 2048 + q * 128 + ln * 8;
#pragma unroll
        for (int ks = 0; ks < 4; ++ks) {
            bf16x8 af = *(const bf16x8*)(a1 + ks * 512);
#pragma unroll
            for (int nt = 0; nt < 2; ++nt) {
                bf16x8 bfr = *(const bf16x8*)&xt[((16 * nt + ln) * 16 + ((4 * ks + q) ^ sw)) * 8];
                acc1[nt] = __builtin_amdgcn_mfma_f32_16x16x32_bf16(af, bfr, acc1[nt], 0, 0, 0);
            }
        }
        // epilogue1: +b1, relu, pack 4 consecutive hid -> ht
        {
            const int hid0 = 16 * w + 4 * q;          // within this 128-slice
            const int ghid = 128 * hf + hid0;
            const float bv0 = b1[ghid + 0], bv1 = b1[ghid + 1];
            const float bv2 = b1[ghid + 2], bv3 = b1[ghid + 3];
            const int c16  = hid0 >> 3;
            const int half = q & 1;
#pragma unroll
            for (int nt = 0; nt < 2; ++nt) {
                const int pt = 16 * nt + ln;
                float v0 = acc1[nt][0] + bv0; v0 = v0 > 0.f ? v0 : 0.f;
                float v1 = acc1[nt][1] + bv1; v1 = v1 > 0.f ? v1 : 0.f;
                float v2 = acc1[nt][2] + bv2; v2 = v2 > 0.f ? v2 : 0.f;
                float v3 = acc1[nt][3] + bv3; v3 = v3 > 0.f ? v3 : 0.f;
                uint2 pk;
                pk.x = (unsigned int)f2bf(v0) | ((unsigned int)f2bf(v1) << 16);
                pk.y = (unsigned int)f2bf(v2) | ((unsigned int)f2bf(v3) << 16);
                ht2[(pt * 16 + (c16 ^ (pt & 7))) * 2 + half] = pk;
            }
        }
        __syncthreads();
        // GEMM2: y += h_slice @ W2_slice (M=32 pts, N=128 ch, K=128); wave w: ch 16w..
        const unsigned short* b2b = W2 + hf * 16384 + w * 2048 + q * 128 + ln * 8;
#pragma unroll
        for (int ks = 0; ks < 4; ++ks) {
            bf16x8 bw = *(const bf16x8*)(b2b + ks * 512);
#pragma unroll
            for (int mt = 0; mt < 2; ++mt) {
                bf16x8 ah = *(const bf16x8*)&ht2[((16 * mt + ln) * 16 + ((4 * ks + q) ^ sw)) * 2];
                acc2[mt] = __builtin_amdgcn_mfma_f32_16x16x32_bf16(ah, bw, acc2[mt], 0, 0, 0);
            }
        }
        __syncthreads();
    }

    // epilogue2: +b2, BN, residual (fp32 base from LDS), write xf (+xt)
    {
        const float* b2   = P.b2s[TF];
        const float* gam  = P.gs[TF];
        const float* bet  = P.bes[TF];
        const float* mean = P.ms[TF];
        const float* var  = P.vvs[TF];
        const int c = 16 * w + ln;
        const float bia = b2[c];
        const float sc  = gam[c] * rsqrtf(var[c] + EPS);
        const float bb  = bet[c];
        const float mu  = mean[c];
#pragma unroll
        for (int mt = 0; mt < 2; ++mt) {
#pragma unroll
            for (int r = 0; r < 4; ++r) {
                const int rl = 16 * mt + 4 * q + r;
                float v  = acc2[mt][r] + bia;
                float y  = (v - mu) * sc + bb;
                float xn = xf32[rl * 128 + c] + y;
                P.xf[(size_t)(p0 + rl) * 128 + c] = xn;
                if constexpr (TV >= 0)
                    xt[(rl * 16 + ((c >> 3) ^ (rl & 7))) * 8 + (c & 7)] = f2bf(xn);
            }
        }
    }

    // ---------------- VFR linear ----------------
    if constexpr (TV >= 0) {
        __syncthreads();
        const unsigned short* VT = P.VTP[TV];
        const float* vb = P.vbb[TV];
        floatx4 acc[2];
#pragma unroll
        for (int i = 0; i < 2; ++i) acc[i] = zero;
        const unsigned short* bb2 = VT + w * 2048 + q * 128 + ln * 8;
#pragma unroll
        for (int ks = 0; ks < 4; ++ks) {
            bf16x8 bw = *(const bf16x8*)(bb2 + ks * 512);
#pragma unroll
            for (int mt = 0; mt < 2; ++mt) {
                bf16x8 ax = *(const bf16x8*)&xt[((16 * mt + ln) * 16 + ((4 * ks + q) ^ sw)) * 8];
                acc[mt] = __builtin_amdgcn_mfma_f32_16x16x32_bf16(ax, bw, acc[mt], 0, 0, 0);
            }
        }
        const int c = 16 * w + ln;
        const float bia = vb[c];
#pragma unroll
        for (int mt = 0; mt < 2; ++mt)
#pragma unroll
            for (int r = 0; r < 4; ++r)
                VbOut[(size_t)(p0 + 16 * mt + 4 * q + r) * 128 + c] = f2bf(acc[mt][r] + bia);
    }
}

// ---------------- launch ----------------
extern "C" void kernel_launch(void* const* d_in, const int* in_sizes, int n_in,
                              void* d_out, int out_size, void* d_ws, size_t ws_size,
                              hipStream_t stream)
{
    Params p;
    p.x_in = (const float*)d_in[0];
    p.knn  = (const int*)d_in[1];
    const float* w1  = (const float*)d_in[2];
    const float* b1  = (const float*)d_in[3];
    const float* w2  = (const float*)d_in[4];
    const float* b2  = (const float*)d_in[5];
    const float* g0  = (const float*)d_in[6];
    const float* be0 = (const float*)d_in[7];
    const float* m0p = (const float*)d_in[8];
    const float* v0p = (const float*)d_in[9];
    const float* vw  = (const float*)d_in[10];
    const float* vbp = (const float*)d_in[11];
    const float* vgp = (const float*)d_in[12];
    const float* vbe = (const float*)d_in[13];
    const float* vmp = (const float*)d_in[14];
    const float* vvp = (const float*)d_in[15];
    const float* fw1 = (const float*)d_in[16];
    const float* fb1 = (const float*)d_in[17];
    const float* fw2 = (const float*)d_in[18];
    const float* fb2 = (const float*)d_in[19];
    const float* fg  = (const float*)d_in[20];
    const float* fbe = (const float*)d_in[21];
    const float* fm  = (const float*)d_in[22];
    const float* fv  = (const float*)d_in[23];

    p.w1s[0] = w1;  p.w1s[1] = fw1; p.w1s[2] = fw1 + 65536;
    p.w2s[0] = w2;  p.w2s[1] = fw2; p.w2s[2] = fw2 + 65536;
    p.vws[0] = vw;  p.vws[1] = vw + 16384;
    p.b1s[0] = b1;  p.b1s[1] = fb1; p.b1s[2] = fb1 + 512;
    p.b2s[0] = b2;  p.b2s[1] = fb2; p.b2s[2] = fb2 + 128;
    p.gs[0]  = g0;  p.gs[1]  = fg;  p.gs[2]  = fg + 128;
    p.bes[0] = be0; p.bes[1] = fbe; p.bes[2] = fbe + 128;
    p.ms[0]  = m0p; p.ms[1]  = fm;  p.ms[2]  = fm + 128;
    p.vvs[0] = v0p; p.vvs[1] = fv;  p.vvs[2] = fv + 128;
    p.vbb[0] = vbp; p.vbb[1] = vbp + 128;
    p.vgg[0] = vgp; p.vgg[1] = vgp + 128;
    p.vbt[0] = vbe; p.vbt[1] = vbe + 128;
    p.vmm[0] = vmp; p.vmm[1] = vmp + 128;
    p.vva[0] = vvp; p.vva[1] = vvp + 128;

    char* ws = (char*)d_ws;
    unsigned short* Vb0 = (unsigned short*)ws;                          // 8 MiB
    unsigned short* Vb1 = (unsigned short*)(ws + (size_t)(8 << 20));    // 8 MiB
    unsigned short* u   = (unsigned short*)(ws + (size_t)(16 << 20));   // packed weights
    for (int i = 0; i < 3; ++i) p.W1P[i] = u + i * 65536;
    for (int i = 0; i < 3; ++i) p.W2P[i] = u + 196608 + i * 65536;
    for (int i = 0; i < 2; ++i) p.VTP[i] = u + 393216 + i * 16384;
    p.xf = (float*)d_out;

    pack2<<<dim3(208), 256, 0, stream>>>(p);
    stage<1, -1, 0, 0><<<dim3(1024), 512, 0, stream>>>(p, p.x_in, nullptr, Vb0);
    stage<0,  0, 1, 1><<<dim3(1024), 512, 0, stream>>>(p, p.xf, Vb0, Vb1);
    stage<0,  1, 2, -1><<<dim3(1024), 512, 0, stream>>>(p, p.xf, Vb1, nullptr);
}

// Round 12
// 183.895 us; speedup vs baseline: 1.1380x; 1.0926x over previous
//
#include <hip/hip_runtime.h>
#include <hip/hip_bf16.h>
#include <stdint.h>

typedef __attribute__((ext_vector_type(8))) __bf16 bf16x8;
typedef __attribute__((ext_vector_type(4))) float floatx4;

#define EPS 1e-5f

__device__ __forceinline__ unsigned short f2bf(float f) {
    union { float f; unsigned int u; } x; x.f = f;
    unsigned int r = x.u + 0x7fffu + ((x.u >> 16) & 1u);
    return (unsigned short)(r >> 16);
}

__device__ __forceinline__ float bf2f(unsigned int u) {
    union { unsigned int u; float f; } x; x.u = u << 16; return x.f;
}

// lgkm-only block barrier: __syncthreads() makes hipcc drain vmcnt(0) too,
// which serializes in-flight (prefetched) global weight loads at EVERY
// barrier. Intra-block correctness here only needs LDS visibility:
// lgkmcnt(0) before s_barrier. "memory" clobber pins LDS ops on both
// sides and forces post-barrier LDS re-reads.
__device__ __forceinline__ void lbar() {
    asm volatile("s_waitcnt lgkmcnt(0)" ::: "memory");
    __builtin_amdgcn_s_barrier();
}

struct Params {
    const float* x_in;
    const int*   knn;
    const float* w1s[3];   // [128][512]
    const float* w2s[3];   // [512][128]
    const float* vws[2];   // [128][128]
    unsigned short* W1P[3];
    unsigned short* W2P[3];
    unsigned short* VTP[2];
    const float* b1s[3];
    const float* b2s[3];
    const float* gs[3];
    const float* bes[3];
    const float* ms[3];
    const float* vvs[3];
    const float* vbb[2];
    const float* vgg[2];
    const float* vbt[2];
    const float* vmm[2];
    const float* vva[2];
    float* xf;
};

// ---------------- pack weights, DEST-major (coalesced uint4 stores) --------
// Validated R3-R10. Fragment layout (consumer side):
// W1P short-addr d = hf*16384 + w*2048 + ks*512 + q*128 + ln*8 + j
//   holds W1[k=32ks+8q+j][h=128hf+16w+ln]   (src [128][512], idx=k*512+h)
// W2P same d-layout, holds W2[h=128hf+32ks+8q+j][c=16w+ln]  (src idx=h*128+c)
// VTP d = w*2048+ks*512+q*128+ln*8+j, holds Wv[k=32ks+8q+j][c=16w+ln]
__global__ __launch_bounds__(256) void pack2(Params P) {
    const int gtid = blockIdx.x * 256 + threadIdx.x;
    unsigned short v[8];
    if (gtid < 24576) {                       // W1 x3: 3*8192 fragments
        const int t = gtid >> 13;
        const int d = (gtid & 8191) << 3;
        const int hf = d >> 14, w = (d >> 11) & 7, ks = (d >> 9) & 3,
                  q = (d >> 7) & 3, ln = (d >> 3) & 15;
        const float* s1 = P.w1s[t];
        const int hcol = 128 * hf + 16 * w + ln;
        const int kb   = 32 * ks + 8 * q;
#pragma unroll
        for (int j = 0; j < 8; ++j) v[j] = f2bf(s1[(kb + j) * 512 + hcol]);
        uint4 pk;
        pk.x = v[0] | ((unsigned)v[1] << 16); pk.y = v[2] | ((unsigned)v[3] << 16);
        pk.z = v[4] | ((unsigned)v[5] << 16); pk.w = v[6] | ((unsigned)v[7] << 16);
        *(uint4*)&P.W1P[t][d] = pk;
    } else if (gtid < 49152) {                // W2 x3: 3*8192 fragments
        const int g = gtid - 24576;
        const int t = g >> 13;
        const int d = (g & 8191) << 3;
        const int hf = d >> 14, w = (d >> 11) & 7, ks = (d >> 9) & 3,
                  q = (d >> 7) & 3, ln = (d >> 3) & 15;
        const float* s2 = P.w2s[t];
        const int col = 16 * w + ln;
        const int hb  = 128 * hf + 32 * ks + 8 * q;
#pragma unroll
        for (int j = 0; j < 8; ++j) v[j] = f2bf(s2[(hb + j) * 128 + col]);
        uint4 pk;
        pk.x = v[0] | ((unsigned)v[1] << 16); pk.y = v[2] | ((unsigned)v[3] << 16);
        pk.z = v[4] | ((unsigned)v[5] << 16); pk.w = v[6] | ((unsigned)v[7] << 16);
        *(uint4*)&P.W2P[t][d] = pk;
    } else if (gtid < 53248) {                // VT x2: 2*2048 fragments
        const int g = gtid - 49152;
        const int t = g >> 11;
        const int d = (g & 2047) << 3;
        const int w = (d >> 11) & 7, ks = (d >> 9) & 3,
                  q = (d >> 7) & 3, ln = (d >> 3) & 15;
        const float* sv = P.vws[t];
        const int col = 16 * w + ln;
        const int kb  = 32 * ks + 8 * q;
#pragma unroll
        for (int j = 0; j < 8; ++j) v[j] = f2bf(sv[(kb + j) * 128 + col]);
        uint4 pk;
        pk.x = v[0] | ((unsigned)v[1] << 16); pk.y = v[2] | ((unsigned)v[3] << 16);
        pk.z = v[4] | ((unsigned)v[5] << 16); pk.w = v[6] | ((unsigned)v[7] << 16);
        *(uint4*)&P.VTP[t][d] = pk;
    }
}

// ---------------- fused stage kernel (512 thr = 8 waves, 64 points) --------
// R6 geometry EXACTLY (best: 183.0 us; R8 pad/R9 hoist/R10 occupancy all
// regressed — stage is BARRIER-DRAIN bound, not conflict/occupancy bound).
// R12 (= R11, resubmitted after infra failure): (a) all __syncthreads ->
// lbar() (lgkmcnt-only barrier; hipcc's __syncthreads drains vmcnt(0) at
// every barrier, serializing weight-load latency into the critical path
// ~10x per stage); (b) cross-barrier weight prefetch now that loads
// survive barriers: W2(hf) issued during GEMM1(hf), W1(hf+1) issued
// during GEMM2(hf), VFR weights issued under epilogue2. VGPR ~90 < 128
// cap of __launch_bounds__(512,4) — no spill expected (WRITE_SIZE
// inflation would be the spill signature).
template <int LOADX, int TE, int TF, int TV>
__global__ __launch_bounds__(512, 4)
void stage(Params P, const float* __restrict__ xold_g,
           const unsigned short* __restrict__ VbIn,
           unsigned short* __restrict__ VbOut)
{
    __shared__ __align__(16) unsigned short xt[8192];   // 16 KB
    __shared__ __align__(16) float xf32[8192];          // 32 KB
    __shared__ __align__(16) uint2 ht2[2048];           // 16 KB
    const int tid  = threadIdx.x;
    const int lane = tid & 63;
    const int w    = tid >> 6;       // wave 0..7
    const int q    = lane >> 4;
    const int ln   = lane & 15;
    const int sw   = ln & 7;
    const int phys = blockIdx.x;
    const int bid  = (phys & 7) * 64 + (phys >> 3);   // XCD-local batches
    const int p0   = bid << 6;
    const floatx4 zero = {0.f, 0.f, 0.f, 0.f};

    if constexpr (LOADX) {
        const int r = tid >> 3, seg = tid & 7;
        const float4* src = (const float4*)(xold_g + (size_t)(p0 + r) * 128 + seg * 16);
        float4* dstf = (float4*)&xf32[r * 128 + seg * 16];
#pragma unroll
        for (int i = 0; i < 2; ++i) {
            float4 a = src[2 * i];
            float4 b = src[2 * i + 1];
            dstf[2 * i]     = a;
            dstf[2 * i + 1] = b;
            int kq = seg * 2 + i;
            uint4 pk;
            pk.x = (unsigned int)f2bf(a.x) | ((unsigned int)f2bf(a.y) << 16);
            pk.y = (unsigned int)f2bf(a.z) | ((unsigned int)f2bf(a.w) << 16);
            pk.z = (unsigned int)f2bf(b.x) | ((unsigned int)f2bf(b.y) << 16);
            pk.w = (unsigned int)f2bf(b.z) | ((unsigned int)f2bf(b.w) << 16);
            *(uint4*)&xt[(r * 16 + (kq ^ (r & 7))) * 8] = pk;
        }
    }

    if constexpr (TE >= 0) {
        const int c0 = lane << 1;
        float2 gv = *(const float2*)(P.vgg[TE] + c0);
        float2 bv = *(const float2*)(P.vbt[TE] + c0);
        float2 mv = *(const float2*)(P.vmm[TE] + c0);
        float2 vv = *(const float2*)(P.vva[TE] + c0);
        const float sc0 = gv.x * rsqrtf(vv.x + EPS);
        const float sc1 = gv.y * rsqrtf(vv.y + EPS);
#pragma unroll
        for (int it = 0; it < 8; ++it) {
            const int pl = it * 8 + w;
            const int p  = p0 + pl;
            const int b  = p >> 12;
            const size_t rowoff = (size_t)p * 128 + c0;
            unsigned int su = *(const unsigned int*)(VbIn + rowoff);
            const int4* kp4 = (const int4*)(P.knn + (size_t)p * 16);
            int4 ka = kp4[0], kb = kp4[1], kc = kp4[2], kd = kp4[3];
            const unsigned short* vbase = VbIn + (((size_t)b << 12) << 7) + c0;
            float m0 = -3.4e38f, m1 = -3.4e38f;
            unsigned int u;
#define GATH(IDX) u = *(const unsigned int*)(vbase + ((size_t)(IDX) << 7)); \
            m0 = fmaxf(m0, bf2f(u & 0xffffu)); m1 = fmaxf(m1, bf2f(u >> 16));
            GATH(ka.x) GATH(ka.y) GATH(ka.z) GATH(ka.w)
            GATH(kb.x) GATH(kb.y) GATH(kb.z) GATH(kb.w)
            GATH(kc.x) GATH(kc.y) GATH(kc.z) GATH(kc.w)
            GATH(kd.x) GATH(kd.y) GATH(kd.z) GATH(kd.w)
#undef GATH
            float s0 = bf2f(su & 0xffffu), s1 = bf2f(su >> 16);
            float y0 = (m0 - s0 - mv.x) * sc0 + bv.x;
            float y1 = (m1 - s1 - mv.y) * sc1 + bv.y;
            float2 xv = *(const float2*)(xold_g + rowoff);
            float xn0 = xv.x + y0, xn1 = xv.y + y1;
            *(float2*)&xf32[pl * 128 + c0] = make_float2(xn0, xn1);
            unsigned int pk = (unsigned int)f2bf(xn0) | ((unsigned int)f2bf(xn1) << 16);
            ((unsigned int*)xt)[(pl * 16 + ((lane >> 2) ^ (pl & 7))) * 4 + (lane & 3)] = pk;
        }
    }
    lbar();

    // ---------------- FFN, hidden-split x4, cross-barrier prefetch --------
    floatx4 acc2[4];
#pragma unroll
    for (int i = 0; i < 4; ++i) acc2[i] = zero;

    const unsigned short* W1 = P.W1P[TF];
    const unsigned short* W2 = P.W2P[TF];
    const float* b1 = P.b1s[TF];
    const unsigned short* a1base = W1 + w * 2048 + q * 128 + ln * 8;
    const unsigned short* b2base = W2 + w * 2048 + q * 128 + ln * 8;

    // prime W1 fragments for hf=0
    bf16x8 afr[4];
#pragma unroll
    for (int ks = 0; ks < 4; ++ks)
        afr[ks] = *(const bf16x8*)(a1base + ks * 512);

#pragma unroll
    for (int hf = 0; hf < 4; ++hf) {
        // issue GEMM2(hf) weight loads NOW — they fly across the e1 barrier
        bf16x8 bwr[4];
#pragma unroll
        for (int ks = 0; ks < 4; ++ks)
            bwr[ks] = *(const bf16x8*)(b2base + hf * 16384 + ks * 512);

        // GEMM1: h^T slice (M=128 hid, N=64 pts, K=128); wave w: hid 16w..16w+15
        floatx4 acc1[4];
#pragma unroll
        for (int i = 0; i < 4; ++i) acc1[i] = zero;
#pragma unroll
        for (int ks = 0; ks < 4; ++ks) {
#pragma unroll
            for (int nt = 0; nt < 4; ++nt) {
                bf16x8 bfr = *(const bf16x8*)&xt[((16 * nt + ln) * 16 + ((4 * ks + q) ^ sw)) * 8];
                acc1[nt] = __builtin_amdgcn_mfma_f32_16x16x32_bf16(afr[ks], bfr, acc1[nt], 0, 0, 0);
            }
        }
        // epilogue1: +b1, relu, pack 4 consecutive hid -> ht
        {
            const int hid0 = 16 * w + 4 * q;          // within this 128-slice
            const int ghid = 128 * hf + hid0;
            const float bv0 = b1[ghid + 0], bv1 = b1[ghid + 1];
            const float bv2 = b1[ghid + 2], bv3 = b1[ghid + 3];
            const int c16  = hid0 >> 3;
            const int half = q & 1;
#pragma unroll
            for (int nt = 0; nt < 4; ++nt) {
                const int pt = 16 * nt + ln;
                float v0 = acc1[nt][0] + bv0; v0 = v0 > 0.f ? v0 : 0.f;
                float v1 = acc1[nt][1] + bv1; v1 = v1 > 0.f ? v1 : 0.f;
                float v2 = acc1[nt][2] + bv2; v2 = v2 > 0.f ? v2 : 0.f;
                float v3 = acc1[nt][3] + bv3; v3 = v3 > 0.f ? v3 : 0.f;
                uint2 pk;
                pk.x = (unsigned int)f2bf(v0) | ((unsigned int)f2bf(v1) << 16);
                pk.y = (unsigned int)f2bf(v2) | ((unsigned int)f2bf(v3) << 16);
                ht2[(pt * 16 + (c16 ^ (pt & 7))) * 2 + half] = pk;
            }
        }
        lbar();
        // issue GEMM1(hf+1) weight loads — they fly across the next barrier
        if (hf < 3) {
#pragma unroll
            for (int ks = 0; ks < 4; ++ks)
                afr[ks] = *(const bf16x8*)(a1base + (hf + 1) * 16384 + ks * 512);
        }
        // GEMM2: y += h_slice @ W2_slice (M=64 pts, N=128 ch, K=128); wave w: ch 16w..
#pragma unroll
        for (int ks = 0; ks < 4; ++ks) {
#pragma unroll
            for (int mt = 0; mt < 4; ++mt) {
                bf16x8 ah = *(const bf16x8*)&ht2[((16 * mt + ln) * 16 + ((4 * ks + q) ^ sw)) * 2];
                acc2[mt] = __builtin_amdgcn_mfma_f32_16x16x32_bf16(ah, bwr[ks], acc2[mt], 0, 0, 0);
            }
        }
        lbar();
    }

    // prefetch VFR weights — they hide under epilogue2's VALU work
    bf16x8 vwr[4];
    if constexpr (TV >= 0) {
        const unsigned short* bb2 = P.VTP[TV] + w * 2048 + q * 128 + ln * 8;
#pragma unroll
        for (int ks = 0; ks < 4; ++ks)
            vwr[ks] = *(const bf16x8*)(bb2 + ks * 512);
    }

    // epilogue2: +b2, BN, residual (fp32 base from LDS), write xf (+xt)
    {
        const float* b2   = P.b2s[TF];
        const float* gam  = P.gs[TF];
        const float* bet  = P.bes[TF];
        const float* mean = P.ms[TF];
        const float* var  = P.vvs[TF];
        const int c = 16 * w + ln;
        const float bia = b2[c];
        const float sc  = gam[c] * rsqrtf(var[c] + EPS);
        const float bb  = bet[c];
        const float mu  = mean[c];
#pragma unroll
        for (int mt = 0; mt < 4; ++mt) {
#pragma unroll
            for (int r = 0; r < 4; ++r) {
                const int rl = 16 * mt + 4 * q + r;
                float v  = acc2[mt][r] + bia;
                float y  = (v - mu) * sc + bb;
                float xn = xf32[rl * 128 + c] + y;
                P.xf[(size_t)(p0 + rl) * 128 + c] = xn;
                if constexpr (TV >= 0)
                    xt[(rl * 16 + ((c >> 3) ^ (rl & 7))) * 8 + (c & 7)] = f2bf(xn);
            }
        }
    }

    // ---------------- VFR linear ----------------
    if constexpr (TV >= 0) {
        lbar();
        const float* vb = P.vbb[TV];
        floatx4 acc[4];
#pragma unroll
        for (int i = 0; i < 4; ++i) acc[i] = zero;
#pragma unroll
        for (int ks = 0; ks < 4; ++ks) {
#pragma unroll
            for (int mt = 0; mt < 4; ++mt) {
                bf16x8 ax = *(const bf16x8*)&xt[((16 * mt + ln) * 16 + ((4 * ks + q) ^ sw)) * 8];
                acc[mt] = __builtin_amdgcn_mfma_f32_16x16x32_bf16(ax, vwr[ks], acc[mt], 0, 0, 0);
            }
        }
        const int c = 16 * w + ln;
        const float bia = vb[c];
#pragma unroll
        for (int mt = 0; mt < 4; ++mt)
#pragma unroll
            for (int r = 0; r < 4; ++r)
                VbOut[(size_t)(p0 + 16 * mt + 4 * q + r) * 128 + c] = f2bf(acc[mt][r] + bia);
    }
}

// ---------------- launch ----------------
extern "C" void kernel_launch(void* const* d_in, const int* in_sizes, int n_in,
                              void* d_out, int out_size, void* d_ws, size_t ws_size,
                              hipStream_t stream)
{
    Params p;
    p.x_in = (const float*)d_in[0];
    p.knn  = (const int*)d_in[1];
    const float* w1  = (const float*)d_in[2];
    const float* b1  = (const float*)d_in[3];
    const float* w2  = (const float*)d_in[4];
    const float* b2  = (const float*)d_in[5];
    const float* g0  = (const float*)d_in[6];
    const float* be0 = (const float*)d_in[7];
    const float* m0p = (const float*)d_in[8];
    const float* v0p = (const float*)d_in[9];
    const float* vw  = (const float*)d_in[10];
    const float* vbp = (const float*)d_in[11];
    const float* vgp = (const float*)d_in[12];
    const float* vbe = (const float*)d_in[13];
    const float* vmp = (const float*)d_in[14];
    const float* vvp = (const float*)d_in[15];
    const float* fw1 = (const float*)d_in[16];
    const float* fb1 = (const float*)d_in[17];
    const float* fw2 = (const float*)d_in[18];
    const float* fb2 = (const float*)d_in[19];
    const float* fg  = (const float*)d_in[20];
    const float* fbe = (const float*)d_in[21];
    const float* fm  = (const float*)d_in[22];
    const float* fv  = (const float*)d_in[23];

    p.w1s[0] = w1;  p.w1s[1] = fw1; p.w1s[2] = fw1 + 65536;
    p.w2s[0] = w2;  p.w2s[1] = fw2; p.w2s[2] = fw2 + 65536;
    p.vws[0] = vw;  p.vws[1] = vw + 16384;
    p.b1s[0] = b1;  p.b1s[1] = fb1; p.b1s[2] = fb1 + 512;
    p.b2s[0] = b2;  p.b2s[1] = fb2; p.b2s[2] = fb2 + 128;
    p.gs[0]  = g0;  p.gs[1]  = fg;  p.gs[2]  = fg + 128;
    p.bes[0] = be0; p.bes[1] = fbe; p.bes[2] = fbe + 128;
    p.ms[0]  = m0p; p.ms[1]  = fm;  p.ms[2]  = fm + 128;
    p.vvs[0] = v0p; p.vvs[1] = fv;  p.vvs[2] = fv + 128;
    p.vbb[0] = vbp; p.vbb[1] = vbp + 128;
    p.vgg[0] = vgp; p.vgg[1] = vgp + 128;
    p.vbt[0] = vbe; p.vbt[1] = vbe + 128;
    p.vmm[0] = vmp; p.vmm[1] = vmp + 128;
    p.vva[0] = vvp; p.vva[1] = vvp + 128;

    char* ws = (char*)d_ws;
    unsigned short* Vb0 = (unsigned short*)ws;                          // 8 MiB
    unsigned short* Vb1 = (unsigned short*)(ws + (size_t)(8 << 20));    // 8 MiB
    unsigned short* u   = (unsigned short*)(ws + (size_t)(16 << 20));   // packed weights
    for (int i = 0; i < 3; ++i) p.W1P[i] = u + i * 65536;
    for (int i = 0; i < 3; ++i) p.W2P[i] = u + 196608 + i * 65536;
    for (int i = 0; i < 2; ++i) p.VTP[i] = u + 393216 + i * 16384;
    p.xf = (float*)d_out;

    pack2<<<dim3(208), 256, 0, stream>>>(p);
    stage<1, -1, 0, 0><<<dim3(512), 512, 0, stream>>>(p, p.x_in, nullptr, Vb0);
    stage<0,  0, 1, 1><<<dim3(512), 512, 0, stream>>>(p, p.xf, Vb0, Vb1);
    stage<0,  1, 2, -1><<<dim3(512), 512, 0, stream>>>(p, p.xf, Vb1, nullptr);
}

// Round 13
// 183.109 us; speedup vs baseline: 1.1429x; 1.0043x over previous
//
#include <hip/hip_runtime.h>
#include <hip/hip_bf16.h>
#include <stdint.h>

typedef __attribute__((ext_vector_type(8))) __bf16 bf16x8;
typedef __attribute__((ext_vector_type(4))) float floatx4;

#define EPS 1e-5f

__device__ __forceinline__ unsigned short f2bf(float f) {
    union { float f; unsigned int u; } x; x.f = f;
    unsigned int r = x.u + 0x7fffu + ((x.u >> 16) & 1u);
    return (unsigned short)(r >> 16);
}

__device__ __forceinline__ float bf2f(unsigned int u) {
    union { unsigned int u; float f; } x; x.u = u << 16; return x.f;
}

// lgkm-only block barrier (R12, proven neutral-correct): drains LDS
// reads+writes so cross-wave LDS deps are safe, but lets global loads
// stay in flight across the barrier.
__device__ __forceinline__ void lbar() {
    asm volatile("s_waitcnt lgkmcnt(0)" ::: "memory");
    __builtin_amdgcn_s_barrier();
}

struct Params {
    const float* x_in;
    const int*   knn;
    const float* w1s[3];   // [128][512]
    const float* w2s[3];   // [512][128]
    const float* vws[2];   // [128][128]
    unsigned short* W1P[3];
    unsigned short* W2P[3];
    unsigned short* VTP[2];
    const float* b1s[3];
    const float* b2s[3];
    const float* gs[3];
    const float* bes[3];
    const float* ms[3];
    const float* vvs[3];
    const float* vbb[2];
    const float* vgg[2];
    const float* vbt[2];
    const float* vmm[2];
    const float* vva[2];
    float* xf;
};

// ---------------- pack weights, DEST-major (coalesced uint4 stores) --------
// Validated R3-R12. Fragment layout (consumer side):
// W1P short-addr d = hf*16384 + w*2048 + ks*512 + q*128 + ln*8 + j
//   holds W1[k=32ks+8q+j][h=128hf+16w+ln]   (src [128][512], idx=k*512+h)
// W2P same d-layout, holds W2[h=128hf+32ks+8q+j][c=16w+ln]  (src idx=h*128+c)
// VTP d = w*2048+ks*512+q*128+ln*8+j, holds Wv[k=32ks+8q+j][c=16w+ln]
__global__ __launch_bounds__(256) void pack2(Params P) {
    const int gtid = blockIdx.x * 256 + threadIdx.x;
    unsigned short v[8];
    if (gtid < 24576) {                       // W1 x3: 3*8192 fragments
        const int t = gtid >> 13;
        const int d = (gtid & 8191) << 3;
        const int hf = d >> 14, w = (d >> 11) & 7, ks = (d >> 9) & 3,
                  q = (d >> 7) & 3, ln = (d >> 3) & 15;
        const float* s1 = P.w1s[t];
        const int hcol = 128 * hf + 16 * w + ln;
        const int kb   = 32 * ks + 8 * q;
#pragma unroll
        for (int j = 0; j < 8; ++j) v[j] = f2bf(s1[(kb + j) * 512 + hcol]);
        uint4 pk;
        pk.x = v[0] | ((unsigned)v[1] << 16); pk.y = v[2] | ((unsigned)v[3] << 16);
        pk.z = v[4] | ((unsigned)v[5] << 16); pk.w = v[6] | ((unsigned)v[7] << 16);
        *(uint4*)&P.W1P[t][d] = pk;
    } else if (gtid < 49152) {                // W2 x3: 3*8192 fragments
        const int g = gtid - 24576;
        const int t = g >> 13;
        const int d = (g & 8191) << 3;
        const int hf = d >> 14, w = (d >> 11) & 7, ks = (d >> 9) & 3,
                  q = (d >> 7) & 3, ln = (d >> 3) & 15;
        const float* s2 = P.w2s[t];
        const int col = 16 * w + ln;
        const int hb  = 128 * hf + 32 * ks + 8 * q;
#pragma unroll
        for (int j = 0; j < 8; ++j) v[j] = f2bf(s2[(hb + j) * 128 + col]);
        uint4 pk;
        pk.x = v[0] | ((unsigned)v[1] << 16); pk.y = v[2] | ((unsigned)v[3] << 16);
        pk.z = v[4] | ((unsigned)v[5] << 16); pk.w = v[6] | ((unsigned)v[7] << 16);
        *(uint4*)&P.W2P[t][d] = pk;
    } else if (gtid < 53248) {                // VT x2: 2*2048 fragments
        const int g = gtid - 49152;
        const int t = g >> 11;
        const int d = (g & 2047) << 3;
        const int w = (d >> 11) & 7, ks = (d >> 9) & 3,
                  q = (d >> 7) & 3, ln = (d >> 3) & 15;
        const float* sv = P.vws[t];
        const int col = 16 * w + ln;
        const int kb  = 32 * ks + 8 * q;
#pragma unroll
        for (int j = 0; j < 8; ++j) v[j] = f2bf(sv[(kb + j) * 128 + col]);
        uint4 pk;
        pk.x = v[0] | ((unsigned)v[1] << 16); pk.y = v[2] | ((unsigned)v[3] << 16);
        pk.z = v[4] | ((unsigned)v[5] << 16); pk.w = v[6] | ((unsigned)v[7] << 16);
        *(uint4*)&P.VTP[t][d] = pk;
    }
}

// ---------------- fused stage kernel (512 thr = 8 waves, 64 points) --------
// R6 geometry + R13 CROSS-PHASE MFMA OVERLAP. History: barrier count (R1),
// conflicts (R8/R9), occupancy (R10), vmcnt drains + weight prefetch (R12)
// all null/negative — every schedule variant lands 183-186 us, yet stages
// run ~4x their compute floor at MfmaUtil 6%. The untested mechanism:
// every region so far held ONE dependency stream (GEMM1->e1->GEMM2 serial).
// R13: double-buffer ht2 and fuse GEMM2(hf-1) with GEMM1(hf) in one
// ks-loop — 8 independent acc chains + e1 VALU per region, FFN barriers
// 8 -> 5. Hazards: e1(hf) writes ht[hf&1] vs GEMM2(hf-1) reads
// ht[(hf-1)&1] (disjoint); ht[r&1] reuse separated by one lbar (lgkmcnt
// drains all waves' ds_reads at the barrier). LDS 80 KB -> 2 blocks/CU.
template <int LOADX, int TE, int TF, int TV>
__global__ __launch_bounds__(512, 4)
void stage(Params P, const float* __restrict__ xold_g,
           const unsigned short* __restrict__ VbIn,
           unsigned short* __restrict__ VbOut)
{
    __shared__ __align__(16) unsigned short xt[8192];   // 16 KB
    __shared__ __align__(16) float xf32[8192];          // 32 KB
    __shared__ __align__(16) uint2 ht2[2][2048];        // 32 KB (dbuf)
    const int tid  = threadIdx.x;
    const int lane = tid & 63;
    const int w    = tid >> 6;       // wave 0..7
    const int q    = lane >> 4;
    const int ln   = lane & 15;
    const int sw   = ln & 7;
    const int phys = blockIdx.x;
    const int bid  = (phys & 7) * 64 + (phys >> 3);   // XCD-local batches
    const int p0   = bid << 6;
    const floatx4 zero = {0.f, 0.f, 0.f, 0.f};

    if constexpr (LOADX) {
        const int r = tid >> 3, seg = tid & 7;
        const float4* src = (const float4*)(xold_g + (size_t)(p0 + r) * 128 + seg * 16);
        float4* dstf = (float4*)&xf32[r * 128 + seg * 16];
#pragma unroll
        for (int i = 0; i < 2; ++i) {
            float4 a = src[2 * i];
            float4 b = src[2 * i + 1];
            dstf[2 * i]     = a;
            dstf[2 * i + 1] = b;
            int kq = seg * 2 + i;
            uint4 pk;
            pk.x = (unsigned int)f2bf(a.x) | ((unsigned int)f2bf(a.y) << 16);
            pk.y = (unsigned int)f2bf(a.z) | ((unsigned int)f2bf(a.w) << 16);
            pk.z = (unsigned int)f2bf(b.x) | ((unsigned int)f2bf(b.y) << 16);
            pk.w = (unsigned int)f2bf(b.z) | ((unsigned int)f2bf(b.w) << 16);
            *(uint4*)&xt[(r * 16 + (kq ^ (r & 7))) * 8] = pk;
        }
    }

    if constexpr (TE >= 0) {
        const int c0 = lane << 1;
        float2 gv = *(const float2*)(P.vgg[TE] + c0);
        float2 bv = *(const float2*)(P.vbt[TE] + c0);
        float2 mv = *(const float2*)(P.vmm[TE] + c0);
        float2 vv = *(const float2*)(P.vva[TE] + c0);
        const float sc0 = gv.x * rsqrtf(vv.x + EPS);
        const float sc1 = gv.y * rsqrtf(vv.y + EPS);
#pragma unroll
        for (int it = 0; it < 8; ++it) {
            const int pl = it * 8 + w;
            const int p  = p0 + pl;
            const int b  = p >> 12;
            const size_t rowoff = (size_t)p * 128 + c0;
            unsigned int su = *(const unsigned int*)(VbIn + rowoff);
            const int4* kp4 = (const int4*)(P.knn + (size_t)p * 16);
            int4 ka = kp4[0], kb = kp4[1], kc = kp4[2], kd = kp4[3];
            const unsigned short* vbase = VbIn + (((size_t)b << 12) << 7) + c0;
            float m0 = -3.4e38f, m1 = -3.4e38f;
            unsigned int u;
#define GATH(IDX) u = *(const unsigned int*)(vbase + ((size_t)(IDX) << 7)); \
            m0 = fmaxf(m0, bf2f(u & 0xffffu)); m1 = fmaxf(m1, bf2f(u >> 16));
            GATH(ka.x) GATH(ka.y) GATH(ka.z) GATH(ka.w)
            GATH(kb.x) GATH(kb.y) GATH(kb.z) GATH(kb.w)
            GATH(kc.x) GATH(kc.y) GATH(kc.z) GATH(kc.w)
            GATH(kd.x) GATH(kd.y) GATH(kd.z) GATH(kd.w)
#undef GATH
            float s0 = bf2f(su & 0xffffu), s1 = bf2f(su >> 16);
            float y0 = (m0 - s0 - mv.x) * sc0 + bv.x;
            float y1 = (m1 - s1 - mv.y) * sc1 + bv.y;
            float2 xv = *(const float2*)(xold_g + rowoff);
            float xn0 = xv.x + y0, xn1 = xv.y + y1;
            *(float2*)&xf32[pl * 128 + c0] = make_float2(xn0, xn1);
            unsigned int pk = (unsigned int)f2bf(xn0) | ((unsigned int)f2bf(xn1) << 16);
            ((unsigned int*)xt)[(pl * 16 + ((lane >> 2) ^ (pl & 7))) * 4 + (lane & 3)] = pk;
        }
    }
    lbar();

    // -------- FFN: dbuf ht2, GEMM2(hf-1) overlapped with GEMM1(hf) --------
    floatx4 acc2[4];
#pragma unroll
    for (int i = 0; i < 4; ++i) acc2[i] = zero;

    const unsigned short* W1 = P.W1P[TF];
    const unsigned short* W2 = P.W2P[TF];
    const float* b1 = P.b1s[TF];
    const unsigned short* a1base = W1 + w * 2048 + q * 128 + ln * 8;
    const unsigned short* b2base = W2 + w * 2048 + q * 128 + ln * 8;

    bf16x8 afr[4];   // W1(hf) fragments
    bf16x8 bwr[4];   // W2(hf) fragments (consumed one region later)
#pragma unroll
    for (int ks = 0; ks < 4; ++ks) {
        afr[ks] = *(const bf16x8*)(a1base + ks * 512);
        bwr[ks] = *(const bf16x8*)(b2base + ks * 512);
    }

    // epilogue1 helper: +b1, relu, pack -> ht2[buf]
    auto e1 = [&](int hf, int buf, floatx4* acc1) {
        const int hid0 = 16 * w + 4 * q;
        const int ghid = 128 * hf + hid0;
        const float bv0 = b1[ghid + 0], bv1 = b1[ghid + 1];
        const float bv2 = b1[ghid + 2], bv3 = b1[ghid + 3];
        const int c16  = hid0 >> 3;
        const int half = q & 1;
#pragma unroll
        for (int nt = 0; nt < 4; ++nt) {
            const int pt = 16 * nt + ln;
            float v0 = acc1[nt][0] + bv0; v0 = v0 > 0.f ? v0 : 0.f;
            float v1 = acc1[nt][1] + bv1; v1 = v1 > 0.f ? v1 : 0.f;
            float v2 = acc1[nt][2] + bv2; v2 = v2 > 0.f ? v2 : 0.f;
            float v3 = acc1[nt][3] + bv3; v3 = v3 > 0.f ? v3 : 0.f;
            uint2 pk;
            pk.x = (unsigned int)f2bf(v0) | ((unsigned int)f2bf(v1) << 16);
            pk.y = (unsigned int)f2bf(v2) | ((unsigned int)f2bf(v3) << 16);
            ht2[buf][(pt * 16 + (c16 ^ (pt & 7))) * 2 + half] = pk;
        }
    };

    // region 0: GEMM1(0) alone -> e1(0) -> ht[0]
    {
        floatx4 acc1[4];
#pragma unroll
        for (int i = 0; i < 4; ++i) acc1[i] = zero;
#pragma unroll
        for (int ks = 0; ks < 4; ++ks) {
#pragma unroll
            for (int nt = 0; nt < 4; ++nt) {
                bf16x8 bfr = *(const bf16x8*)&xt[((16 * nt + ln) * 16 + ((4 * ks + q) ^ sw)) * 8];
                acc1[nt] = __builtin_amdgcn_mfma_f32_16x16x32_bf16(afr[ks], bfr, acc1[nt], 0, 0, 0);
            }
        }
        // reload afr = W1(1) — flies across the barrier
#pragma unroll
        for (int ks = 0; ks < 4; ++ks)
            afr[ks] = *(const bf16x8*)(a1base + 16384 + ks * 512);
        e1(0, 0, acc1);
    }
    lbar();

    // regions 1..3: GEMM2(hf-1) [ht[(hf-1)&1], bwr] ∥ GEMM1(hf) [xt, afr]
#pragma unroll
    for (int hf = 1; hf < 4; ++hf) {
        const int rbuf = (hf - 1) & 1;
        floatx4 acc1[4];
#pragma unroll
        for (int i = 0; i < 4; ++i) acc1[i] = zero;
#pragma unroll
        for (int ks = 0; ks < 4; ++ks) {
#pragma unroll
            for (int nt = 0; nt < 4; ++nt) {
                bf16x8 bfr = *(const bf16x8*)&xt[((16 * nt + ln) * 16 + ((4 * ks + q) ^ sw)) * 8];
                acc1[nt] = __builtin_amdgcn_mfma_f32_16x16x32_bf16(afr[ks], bfr, acc1[nt], 0, 0, 0);
                bf16x8 ah = *(const bf16x8*)&ht2[rbuf][((16 * nt + ln) * 16 + ((4 * ks + q) ^ sw)) * 2];
                acc2[nt] = __builtin_amdgcn_mfma_f32_16x16x32_bf16(ah, bwr[ks], acc2[nt], 0, 0, 0);
            }
        }
        // reload weight regs for the next region (cross-barrier flight)
#pragma unroll
        for (int ks = 0; ks < 4; ++ks) {
            bwr[ks] = *(const bf16x8*)(b2base + hf * 16384 + ks * 512);
            if (hf < 3)
                afr[ks] = *(const bf16x8*)(a1base + (hf + 1) * 16384 + ks * 512);
        }
        e1(hf, hf & 1, acc1);
        lbar();
    }

    // tail: GEMM2(3) from ht[1]
#pragma unroll
    for (int ks = 0; ks < 4; ++ks) {
#pragma unroll
        for (int mt = 0; mt < 4; ++mt) {
            bf16x8 ah = *(const bf16x8*)&ht2[1][((16 * mt + ln) * 16 + ((4 * ks + q) ^ sw)) * 2];
            acc2[mt] = __builtin_amdgcn_mfma_f32_16x16x32_bf16(ah, bwr[ks], acc2[mt], 0, 0, 0);
        }
    }

    // prefetch VFR weights — hide under epilogue2's VALU work
    bf16x8 vwr[4];
    if constexpr (TV >= 0) {
        const unsigned short* bb2 = P.VTP[TV] + w * 2048 + q * 128 + ln * 8;
#pragma unroll
        for (int ks = 0; ks < 4; ++ks)
            vwr[ks] = *(const bf16x8*)(bb2 + ks * 512);
    }

    // epilogue2: +b2, BN, residual (fp32 base from LDS), write xf (+xt)
    {
        const float* b2   = P.b2s[TF];
        const float* gam  = P.gs[TF];
        const float* bet  = P.bes[TF];
        const float* mean = P.ms[TF];
        const float* var  = P.vvs[TF];
        const int c = 16 * w + ln;
        const float bia = b2[c];
        const float sc  = gam[c] * rsqrtf(var[c] + EPS);
        const float bb  = bet[c];
        const float mu  = mean[c];
#pragma unroll
        for (int mt = 0; mt < 4; ++mt) {
#pragma unroll
            for (int r = 0; r < 4; ++r) {
                const int rl = 16 * mt + 4 * q + r;
                float v  = acc2[mt][r] + bia;
                float y  = (v - mu) * sc + bb;
                float xn = xf32[rl * 128 + c] + y;
                P.xf[(size_t)(p0 + rl) * 128 + c] = xn;
                if constexpr (TV >= 0)
                    xt[(rl * 16 + ((c >> 3) ^ (rl & 7))) * 8 + (c & 7)] = f2bf(xn);
            }
        }
    }

    // ---------------- VFR linear ----------------
    if constexpr (TV >= 0) {
        lbar();
        const float* vb = P.vbb[TV];
        floatx4 acc[4];
#pragma unroll
        for (int i = 0; i < 4; ++i) acc[i] = zero;
#pragma unroll
        for (int ks = 0; ks < 4; ++ks) {
#pragma unroll
            for (int mt = 0; mt < 4; ++mt) {
                bf16x8 ax = *(const bf16x8*)&xt[((16 * mt + ln) * 16 + ((4 * ks + q) ^ sw)) * 8];
                acc[mt] = __builtin_amdgcn_mfma_f32_16x16x32_bf16(ax, vwr[ks], acc[mt], 0, 0, 0);
            }
        }
        const int c = 16 * w + ln;
        const float bia = vb[c];
#pragma unroll
        for (int mt = 0; mt < 4; ++mt)
#pragma unroll
            for (int r = 0; r < 4; ++r)
                VbOut[(size_t)(p0 + 16 * mt + 4 * q + r) * 128 + c] = f2bf(acc[mt][r] + bia);
    }
}

// ---------------- launch ----------------
extern "C" void kernel_launch(void* const* d_in, const int* in_sizes, int n_in,
                              void* d_out, int out_size, void* d_ws, size_t ws_size,
                              hipStream_t stream)
{
    Params p;
    p.x_in = (const float*)d_in[0];
    p.knn  = (const int*)d_in[1];
    const float* w1  = (const float*)d_in[2];
    const float* b1  = (const float*)d_in[3];
    const float* w2  = (const float*)d_in[4];
    const float* b2  = (const float*)d_in[5];
    const float* g0  = (const float*)d_in[6];
    const float* be0 = (const float*)d_in[7];
    const float* m0p = (const float*)d_in[8];
    const float* v0p = (const float*)d_in[9];
    const float* vw  = (const float*)d_in[10];
    const float* vbp = (const float*)d_in[11];
    const float* vgp = (const float*)d_in[12];
    const float* vbe = (const float*)d_in[13];
    const float* vmp = (const float*)d_in[14];
    const float* vvp = (const float*)d_in[15];
    const float* fw1 = (const float*)d_in[16];
    const float* fb1 = (const float*)d_in[17];
    const float* fw2 = (const float*)d_in[18];
    const float* fb2 = (const float*)d_in[19];
    const float* fg  = (const float*)d_in[20];
    const float* fbe = (const float*)d_in[21];
    const float* fm  = (const float*)d_in[22];
    const float* fv  = (const float*)d_in[23];

    p.w1s[0] = w1;  p.w1s[1] = fw1; p.w1s[2] = fw1 + 65536;
    p.w2s[0] = w2;  p.w2s[1] = fw2; p.w2s[2] = fw2 + 65536;
    p.vws[0] = vw;  p.vws[1] = vw + 16384;
    p.b1s[0] = b1;  p.b1s[1] = fb1; p.b1s[2] = fb1 + 512;
    p.b2s[0] = b2;  p.b2s[1] = fb2; p.b2s[2] = fb2 + 128;
    p.gs[0]  = g0;  p.gs[1]  = fg;  p.gs[2]  = fg + 128;
    p.bes[0] = be0; p.bes[1] = fbe; p.bes[2] = fbe + 128;
    p.ms[0]  = m0p; p.ms[1]  = fm;  p.ms[2]  = fm + 128;
    p.vvs[0] = v0p; p.vvs[1] = fv;  p.vvs[2] = fv + 128;
    p.vbb[0] = vbp; p.vbb[1] = vbp + 128;
    p.vgg[0] = vgp; p.vgg[1] = vgp + 128;
    p.vbt[0] = vbe; p.vbt[1] = vbe + 128;
    p.vmm[0] = vmp; p.vmm[1] = vmp + 128;
    p.vva[0] = vvp; p.vva[1] = vvp + 128;

    char* ws = (char*)d_ws;
    unsigned short* Vb0 = (unsigned short*)ws;                          // 8 MiB
    unsigned short* Vb1 = (unsigned short*)(ws + (size_t)(8 << 20));    // 8 MiB
    unsigned short* u   = (unsigned short*)(ws + (size_t)(16 << 20));   // packed weights
    for (int i = 0; i < 3; ++i) p.W1P[i] = u + i * 65536;
    for (int i = 0; i < 3; ++i) p.W2P[i] = u + 196608 + i * 65536;
    for (int i = 0; i < 2; ++i) p.VTP[i] = u + 393216 + i * 16384;
    p.xf = (float*)d_out;

    pack2<<<dim3(208), 256, 0, stream>>>(p);
    stage<1, -1, 0, 0><<<dim3(512), 512, 0, stream>>>(p, p.x_in, nullptr, Vb0);
    stage<0,  0, 1, 1><<<dim3(512), 512, 0, stream>>>(p, p.xf, Vb0, Vb1);
    stage<0,  1, 2, -1><<<dim3(512), 512, 0, stream>>>(p, p.xf, Vb1, nullptr);
}